// Round 10
// baseline (351.969 us; speedup 1.0000x reference)
//
#include <hip/hip_runtime.h>

#define N_NODES 20000
#define N_EDGES 320000
#define N_FEAT 128
#define MLP_HID 64
#define N_GRAPHS 16
#define N_LAYERS 5
#define EPS 1e-5f
#define NCHUNK 5000  // scatter blocks per pass (4 nodes/block)

typedef __attribute__((ext_vector_type(8))) short short8;   // 8 bf16 = 4 VGPRs (MFMA A/B frag)
typedef __attribute__((ext_vector_type(4))) float f32x4;    // MFMA C/D frag

__device__ inline float bf2f(unsigned short u) { return __uint_as_float(((unsigned)u) << 16); }
__device__ inline unsigned short f2bf(float f) {
  unsigned u = __float_as_uint(f);
  u += 0x7FFF + ((u >> 16) & 1);  // RNE
  return (unsigned short)(u >> 16);
}

// ---------------- weight prep: bf16 + transpose (once per call); also zeroes deg ----------------

__global__ __launch_bounds__(256) void k_prep(const float* __restrict__ W1, const float* __restrict__ W2,
                                              unsigned short* __restrict__ w1t, unsigned short* __restrict__ w2t,
                                              int* __restrict__ deg) {
  int idx = blockIdx.x * 256 + threadIdx.x;  // grid exact: 320*256 = 81920
  if (idx < N_NODES) deg[idx] = 0;
  if (idx < 40960) {
    int l = idx >> 13, rem = idx & 8191;
    int n = rem >> 7, k = rem & 127;
    w1t[idx] = f2bf(W1[l * 8192 + k * 64 + n]);
  } else {
    int j = idx - 40960;
    int l = j >> 13, rem = j & 8191;
    int n = rem >> 6, k = rem & 63;
    w2t[j] = f2bf(W2[l * 8192 + k * 128 + n]);
  }
}

// ---------------- CSR build ----------------

__global__ __launch_bounds__(256) void k_deg(const int* __restrict__ dst, int* __restrict__ deg) {
  int e = blockIdx.x * 256 + threadIdx.x;  // grid exact: 1250*256 = 320000
  atomicAdd(&deg[dst[e]], 1);
}

__global__ __launch_bounds__(1024) void k_scan(const int* __restrict__ deg, int* __restrict__ rowptr,
                                               int* __restrict__ cursor, const int* __restrict__ batch,
                                               float* __restrict__ cntf, float* __restrict__ pooled) {
  __shared__ int sdata[1024];
  __shared__ int spos[17];
  constexpr int CH = 20;  // 1024*20 = 20480 >= 20000
  int t = threadIdx.x;
  for (int i = t; i < N_GRAPHS * N_FEAT; i += 1024) pooled[i] = 0.0f;
  int base = t * CH;
  int loc[CH];
  int partial = 0;
#pragma unroll
  for (int i = 0; i < CH; i++) {
    int idx = base + i;
    int v = (idx < N_NODES) ? deg[idx] : 0;
    loc[i] = v;
    partial += v;
  }
  sdata[t] = partial;
  __syncthreads();
  for (int off = 1; off < 1024; off <<= 1) {
    int v = (t >= off) ? sdata[t - off] : 0;
    __syncthreads();
    sdata[t] += v;
    __syncthreads();
  }
  int run = sdata[t] - partial;  // exclusive prefix
#pragma unroll
  for (int i = 0; i < CH; i++) {
    int idx = base + i;
    if (idx < N_NODES) {
      rowptr[idx] = run;
      cursor[idx] = run;
      run += loc[i];
    }
  }
  if (t == 1023) rowptr[N_NODES] = sdata[1023];
  if (t < 17) {  // per-graph counts via binary search on sorted batch
    int lo = 0, hi = N_NODES;
    while (lo < hi) {
      int mid = (lo + hi) >> 1;
      if (batch[mid] < t) lo = mid + 1; else hi = mid;
    }
    spos[t] = lo;
  }
  __syncthreads();
  if (t < N_GRAPHS) cntf[t] = fmaxf((float)(spos[t + 1] - spos[t]), 1.0f);
}

__global__ __launch_bounds__(256) void k_fill(const int* __restrict__ src, const int* __restrict__ dst,
                                              int* __restrict__ cursor, unsigned short* __restrict__ src_sorted) {
  int e = blockIdx.x * 256 + threadIdx.x;  // grid exact
  int d = dst[e];
  int p = atomicAdd(&cursor[d], 1);
  src_sorted[p] = (unsigned short)src[e];  // N_NODES=20000 < 65536
}

// ---------------- per-node MLP via MFMA: m = relu(h@W1+b1)@W2+b2 ----------------
// m stored as TWO contiguous half-feature buffers m_lo[n][64], m_hi[n][64] (bf16, 2.56MB each)
// so each scatter pass's gather working set fits a 4MB per-XCD L2.
// fp32in=1: hin is fp32 (layer 0 reads x); else bf16 (hbuf).

#define PADK 136  // 128+8 shorts: +16B row pad breaks LDS bank conflicts
#define PADH 72   // 64+8

__global__ __launch_bounds__(256) void k_mlp(const float* __restrict__ hinf,
                                             const unsigned short* __restrict__ hinb, int fp32in,
                                             unsigned short* __restrict__ mlo,
                                             unsigned short* __restrict__ mhi,
                                             const unsigned short* __restrict__ w1t,
                                             const unsigned short* __restrict__ w2t,
                                             const float* __restrict__ b1, const float* __restrict__ b2) {
  __shared__ __align__(16) short hS[64 * PADK];   // h bf16; reused as m-out after phase 1
  __shared__ __align__(16) short w1S[64 * PADK];  // W1^T [n][k]
  __shared__ __align__(16) short hidS[64 * PADH]; // hidden [m][k]
  __shared__ __align__(16) short w2S[128 * PADH]; // W2^T [n][k]
  __shared__ float b1S[64];
  __shared__ float b2S[128];
  int t = threadIdx.x;
  int r0 = blockIdx.x * 64;  // grid 313: last block covers 32 valid rows
  if (fp32in) {  // stage h (fp32 global -> bf16 LDS)
#pragma unroll
    for (int i = 0; i < 8; i++) {
      int idx = t + i * 256;  // float4 id, 2048 total
      int row = idx >> 5, c4 = idx & 31;
      float4 v = (r0 + row < N_NODES) ? ((const float4*)hinf)[(size_t)(r0 + row) * 32 + c4]
                                      : make_float4(0.f, 0.f, 0.f, 0.f);
      ushort4 s;
      s.x = f2bf(v.x); s.y = f2bf(v.y); s.z = f2bf(v.z); s.w = f2bf(v.w);
      *(ushort4*)&hS[row * PADK + c4 * 4] = s;
    }
  } else {  // stage h (bf16 global -> bf16 LDS, pure copy)
#pragma unroll
    for (int i = 0; i < 4; i++) {
      int idx = t + i * 256;  // int4 id, 1024 total (64 rows x 16 chunks)
      int row = idx >> 4, c8 = idx & 15;
      int4 v = (r0 + row < N_NODES) ? ((const int4*)hinb)[(size_t)(r0 + row) * 16 + c8]
                                    : make_int4(0, 0, 0, 0);
      *(int4*)&hS[row * PADK + c8 * 8] = v;
    }
  }
  // stage W1t (64x128 shorts = 1024 16B chunks) and W2t (128x64)
#pragma unroll
  for (int i = 0; i < 4; i++) {
    int idx = t + i * 256;
    *(int4*)&w1S[(idx >> 4) * PADK + (idx & 15) * 8] = ((const int4*)w1t)[idx];
    *(int4*)&w2S[(idx >> 3) * PADH + (idx & 7) * 8] = ((const int4*)w2t)[idx];
  }
  if (t < 64) b1S[t] = b1[t];
  else if (t < 192) b2S[t - 64] = b2[t - 64];
  __syncthreads();

  int w = t >> 6, lane = t & 63, lm = lane & 15, quad = lane >> 4;
  int mrow = w * 16 + lm;          // A-operand row for this lane
  int orow = w * 16 + quad * 4;    // C/D base row for this lane

  // phase 1: hid[64][64] = relu(h @ W1 + b1)
  f32x4 zero = {0.f, 0.f, 0.f, 0.f};
  f32x4 acc[4] = {zero, zero, zero, zero};
#pragma unroll
  for (int k0 = 0; k0 < 128; k0 += 32) {
    short8 a = *(const short8*)&hS[mrow * PADK + k0 + quad * 8];
#pragma unroll
    for (int nt = 0; nt < 4; nt++) {
      short8 b = *(const short8*)&w1S[(nt * 16 + lm) * PADK + k0 + quad * 8];
      acc[nt] = __builtin_amdgcn_mfma_f32_16x16x32_bf16(a, b, acc[nt], 0, 0, 0);
    }
  }
#pragma unroll
  for (int nt = 0; nt < 4; nt++) {
    int col = nt * 16 + lm;
    float bb = b1S[col];
#pragma unroll
    for (int r = 0; r < 4; r++)
      hidS[(orow + r) * PADH + col] = (short)f2bf(fmaxf(acc[nt][r] + bb, 0.0f));
  }
  __syncthreads();  // hidS ready; hS no longer read -> reusable as m-out

  // phase 2: m[64][128] = hid @ W2 + b2
  f32x4 acc2[8] = {zero, zero, zero, zero, zero, zero, zero, zero};
#pragma unroll
  for (int k0 = 0; k0 < 64; k0 += 32) {
    short8 a = *(const short8*)&hidS[mrow * PADH + k0 + quad * 8];
#pragma unroll
    for (int nt = 0; nt < 8; nt++) {
      short8 b = *(const short8*)&w2S[(nt * 16 + lm) * PADH + k0 + quad * 8];
      acc2[nt] = __builtin_amdgcn_mfma_f32_16x16x32_bf16(a, b, acc2[nt], 0, 0, 0);
    }
  }
#pragma unroll
  for (int nt = 0; nt < 8; nt++) {
    int col = nt * 16 + lm;
    float bb = b2S[col];
#pragma unroll
    for (int r = 0; r < 4; r++)
      hS[(orow + r) * PADK + col] = (short)f2bf(acc2[nt][r] + bb);
  }
  __syncthreads();
  // coalesced bf16 store of m into the two half buffers
#pragma unroll
  for (int i = 0; i < 4; i++) {
    int idx = t + i * 256;
    int row = idx >> 4, cc = idx & 15;
    if (r0 + row < N_NODES) {
      int4 v = *(const int4*)&hS[row * PADK + cc * 8];
      if (cc < 8) ((int4*)mlo)[(size_t)(r0 + row) * 8 + cc] = v;
      else        ((int4*)mhi)[(size_t)(r0 + row) * 8 + (cc - 8)] = v;
    }
  }
}

// ---------------- scatter-add, 2 half-feature passes: g[n] = m[n] + sum m[src[e]] ----------------
// pass = blockIdx/NCHUNK (0: m_lo, 1: m_hi); pass-0 blocks dispatch first.
// Working set per pass: half-buffer 2.56MB + srcs 0.64MB + rowptr 0.08MB < 4MB per-XCD L2.
// Per wave: 1 node; 8 edge slots x 8 lanes; each edge's 128B half-row = exactly 1 cacheline.
// No LDS, no barrier (wave-independent retirement).

__global__ __launch_bounds__(256) void k_scatter(const unsigned short* __restrict__ mlo,
                                                 const unsigned short* __restrict__ mhi,
                                                 unsigned short* __restrict__ g,
                                                 const int* __restrict__ rowptr,
                                                 const unsigned short* __restrict__ srcs,
                                                 float* __restrict__ s1, float* __restrict__ s2) {
  if (blockIdx.x == 0) {  // zero stats accumulators (k_stats dispatches later)
    for (int i = threadIdx.x; i < N_GRAPHS * N_FEAT; i += 256) { s1[i] = 0.0f; s2[i] = 0.0f; }
  }
  int pass = blockIdx.x / NCHUNK;          // grid = 2*NCHUNK
  int chunk = blockIdx.x - pass * NCHUNK;
  int t = threadIdx.x;
  int node = chunk * 4 + (t >> 6);
  int lane = t & 63;
  int egrp = lane >> 3;   // 8 edge slots per wave
  int c8 = lane & 7;      // 16B sub-chunk within the 128B half-row
  const float4* m4 = (const float4*)(pass ? mhi : mlo);
  float acc[8];
  union BU { float4 f; unsigned short u[8]; };
  if (egrp == 0) {  // self loop
    BU U; U.f = m4[(size_t)node * 8 + c8];
#pragma unroll
    for (int j = 0; j < 8; j++) acc[j] = bf2f(U.u[j]);
  } else {
#pragma unroll
    for (int j = 0; j < 8; j++) acc[j] = 0.0f;
  }
  int e = rowptr[node] + egrp, e1 = rowptr[node + 1];
  for (; e + 8 < e1; e += 16) {  // 2-deep unroll: both loads in flight
    int i0 = srcs[e];
    int i1 = srcs[e + 8];
    BU U0, U1;
    U0.f = m4[(size_t)i0 * 8 + c8];
    U1.f = m4[(size_t)i1 * 8 + c8];
#pragma unroll
    for (int j = 0; j < 8; j++) acc[j] += bf2f(U0.u[j]) + bf2f(U1.u[j]);
  }
  if (e < e1) {
    BU U0; U0.f = m4[(size_t)srcs[e] * 8 + c8];
#pragma unroll
    for (int j = 0; j < 8; j++) acc[j] += bf2f(U0.u[j]);
  }
#pragma unroll
  for (int j = 0; j < 8; j++) {  // reduce across the 8 edge slots (lane bits 3..5)
    acc[j] += __shfl_xor(acc[j], 8);
    acc[j] += __shfl_xor(acc[j], 16);
    acc[j] += __shfl_xor(acc[j], 32);
  }
  if (egrp == 0) {
    union { int4 i4; unsigned short u[8]; } P;
#pragma unroll
    for (int j = 0; j < 8; j++) P.u[j] = f2bf(acc[j]);
    ((int4*)g)[(size_t)node * 16 + pass * 8 + c8] = P.i4;  // disjoint 128B line per pass
  }
}

// ---------------- one-pass segment stats over bf16 g: s1 = sum(g), s2 = sum(g^2) ----------------

#define STAT_CHUNK 8  // 2500 blocks * 8 = 20000 exact

__global__ __launch_bounds__(128) void k_stats(const unsigned short* __restrict__ in,
                                               const int* __restrict__ batch,
                                               float* __restrict__ s1, float* __restrict__ s2) {
  int n0 = blockIdx.x * STAT_CHUNK;
  int c = threadIdx.x;
  int curg = batch[n0];
  float a1 = 0.0f, a2 = 0.0f;
#pragma unroll
  for (int k = 0; k < STAT_CHUNK; k++) {
    int n = n0 + k;
    int gg = batch[n];
    if (gg != curg) {  // block-uniform branch (batch sorted)
      atomicAdd(&s1[curg * 128 + c], a1);
      atomicAdd(&s2[curg * 128 + c], a2);
      a1 = 0.0f; a2 = 0.0f;
      curg = gg;
    }
    float v = bf2f(in[(size_t)n * 128 + c]);
    a1 += v;
    a2 += v * v;
  }
  atomicAdd(&s1[curg * 128 + c], a1);
  atomicAdd(&s2[curg * 128 + c], a2);
}

// ---------------- normalize + affine + relu + residual; g,h bf16 ----------------
// var = E[(h - a*mean)^2] = E[h^2] - mean^2*(2a - a^2)

__global__ __launch_bounds__(256) void k_apply(const unsigned short* __restrict__ gin,
                                               unsigned short* __restrict__ h,
                                               const int* __restrict__ batch,
                                               const float* __restrict__ s1, const float* __restrict__ s2,
                                               const float* __restrict__ cntf,
                                               const float* __restrict__ w, const float* __restrict__ b,
                                               const float* __restrict__ a, int residual) {
  int idx = blockIdx.x * 256 + threadIdx.x;  // 4-channel index; grid exact: 2500*256 = 640,000
  int n = idx >> 5, c4 = idx & 31;
  int gg = batch[n];
  float invc = 1.0f / cntf[gg];
  float4 sm = ((const float4*)s1)[gg * 32 + c4];
  float4 se = ((const float4*)s2)[gg * 32 + c4];
  float4 av = ((const float4*)a)[c4];
  float4 wv = ((const float4*)w)[c4];
  float4 bv = ((const float4*)b)[c4];
  ushort4 gu = ((const ushort4*)gin)[idx];
  float4 gv = make_float4(bf2f(gu.x), bf2f(gu.y), bf2f(gu.z), bf2f(gu.w));
  float4 hv = make_float4(0.f, 0.f, 0.f, 0.f);
  if (residual) {
    ushort4 hu = ((const ushort4*)h)[idx];
    hv = make_float4(bf2f(hu.x), bf2f(hu.y), bf2f(hu.z), bf2f(hu.w));
  }
  float4 o;
#define APPLY1(X)                                                          \
  {                                                                        \
    float mean = sm.X * invc;                                              \
    float ex2 = se.X * invc;                                               \
    float ac = av.X;                                                       \
    float var = fmaxf(ex2 - mean * mean * (2.0f * ac - ac * ac), 0.0f);    \
    float d = gv.X - ac * mean;                                            \
    float y = wv.X * (d * rsqrtf(var + EPS)) + bv.X;                       \
    y = fmaxf(y, 0.0f);                                                    \
    o.X = residual ? (y + hv.X) : y;                                       \
  }
  APPLY1(x) APPLY1(y) APPLY1(z) APPLY1(w)
#undef APPLY1
  ushort4 ou;
  ou.x = f2bf(o.x); ou.y = f2bf(o.y); ou.z = f2bf(o.z); ou.w = f2bf(o.w);
  ((ushort4*)h)[idx] = ou;
}

// ---------------- last layer: apply + pooled segment-sum (h never materialized) ----------------

__global__ __launch_bounds__(256) void k_apply_pool(const unsigned short* __restrict__ gin,
                                                    const unsigned short* __restrict__ h,
                                                    const int* __restrict__ batch,
                                                    const float* __restrict__ s1, const float* __restrict__ s2,
                                                    const float* __restrict__ cntf,
                                                    const float* __restrict__ gw, const float* __restrict__ gb,
                                                    const float* __restrict__ ga,
                                                    float* __restrict__ pooled) {
  __shared__ float pS[8][128];
  int t = threadIdx.x;
  int idx = blockIdx.x * 256 + t;  // 4-channel index; grid exact: 2500*256
  int n = idx >> 5, c4 = idx & 31;
  int gg = batch[n];
  float invc = 1.0f / cntf[gg];
  float4 sm = ((const float4*)s1)[gg * 32 + c4];
  float4 se = ((const float4*)s2)[gg * 32 + c4];
  float4 av = ((const float4*)ga)[c4];
  float4 wv = ((const float4*)gw)[c4];
  float4 bv = ((const float4*)gb)[c4];
  ushort4 gu = ((const ushort4*)gin)[idx];
  float4 gv = make_float4(bf2f(gu.x), bf2f(gu.y), bf2f(gu.z), bf2f(gu.w));
  ushort4 hu = ((const ushort4*)h)[idx];  // residual (layer 5 always has it)
  float4 hv = make_float4(bf2f(hu.x), bf2f(hu.y), bf2f(hu.z), bf2f(hu.w));
  float4 o;
#define APPLY1(X)                                                          \
  {                                                                        \
    float mean = sm.X * invc;                                              \
    float ex2 = se.X * invc;                                               \
    float ac = av.X;                                                       \
    float var = fmaxf(ex2 - mean * mean * (2.0f * ac - ac * ac), 0.0f);    \
    float d = gv.X - ac * mean;                                            \
    float y = wv.X * (d * rsqrtf(var + EPS)) + bv.X;                       \
    y = fmaxf(y, 0.0f);                                                    \
    o.X = y + hv.X;                                                        \
  }
  APPLY1(x) APPLY1(y) APPLY1(z) APPLY1(w)
#undef APPLY1
  *(float4*)&pS[t >> 5][c4 * 4] = o;
  __syncthreads();
  int n0 = blockIdx.x * 8;
  int gA = batch[n0], gB = batch[n0 + 7];
  if (t < 128) {
    if (gA == gB) {
      float s = 0.f;
#pragma unroll
      for (int ww = 0; ww < 8; ww++) s += pS[ww][t];
      atomicAdd(&pooled[gA * 128 + t], s);
    } else {
#pragma unroll
      for (int ww = 0; ww < 8; ww++) atomicAdd(&pooled[batch[n0 + ww] * 128 + t], pS[ww][t]);
    }
  }
}

// ---------------- final pooled @ lin_w + lin_b ----------------

__global__ __launch_bounds__(256) void k_final(const float* __restrict__ pooled, const float* __restrict__ cntf,
                                               const float* __restrict__ lw, const float* __restrict__ lb,
                                               float* __restrict__ out) {
  int lane = threadIdx.x & 63, wave = threadIdx.x >> 6;
  for (int gi = 0; gi < 4; gi++) {
    int gidx = wave * 4 + gi;
    float s = pooled[gidx * 128 + lane] * lw[lane] + pooled[gidx * 128 + 64 + lane] * lw[64 + lane];
    for (int o = 32; o >= 1; o >>= 1) s += __shfl_down(s, o);
    if (lane == 0) out[gidx] = s / cntf[gidx] + lb[0];
  }
}

// ---------------- host ----------------

extern "C" void kernel_launch(void* const* d_in, const int* in_sizes, int n_in,
                              void* d_out, int out_size, void* d_ws, size_t ws_size,
                              hipStream_t stream) {
  const float* x = (const float*)d_in[0];
  const int* ei = (const int*)d_in[1];
  const int* batch = (const int*)d_in[2];
  const float* W1 = (const float*)d_in[3];
  const float* b1 = (const float*)d_in[4];
  const float* W2 = (const float*)d_in[5];
  const float* b2 = (const float*)d_in[6];
  const float* gnw = (const float*)d_in[7];
  const float* gnb = (const float*)d_in[8];
  const float* gna = (const float*)d_in[9];
  const float* lw = (const float*)d_in[10];
  const float* lb = (const float*)d_in[11];
  float* out = (float*)d_out;

  const int* srcI = ei;
  const int* dstI = ei + N_EDGES;

  char* p = (char*)d_ws;
  unsigned short* hbuf = (unsigned short*)(p + 0);         // 5,120,000 B (bf16)
  unsigned short* mlo = (unsigned short*)(p + 10240000);   // 2,560,000 B (bf16 half-features)
  unsigned short* mhi = (unsigned short*)(p + 12800000);   // 2,560,000 B
  unsigned short* gbuf = (unsigned short*)(p + 20480000);  // 5,120,000 B (bf16)
  unsigned short* src_sorted = (unsigned short*)(p + 30720000);  // 640,000 B (u16 node ids)
  int* rowptr = (int*)(p + 32000000);
  int* cursor = (int*)(p + 32080128);
  int* deg = (int*)(p + 32160256);
  float* cntf = (float*)(p + 32240512);
  float* s1buf = (float*)(p + 32240640);                   // 8192 B
  float* s2buf = (float*)(p + 32248832);                   // 8192 B
  float* pooled = (float*)(p + 32257024);                  // 8192 B
  unsigned short* w1t = (unsigned short*)(p + 32265216);   // 81,920 B (5 layers bf16 W1^T)
  unsigned short* w2t = (unsigned short*)(p + 32347136);   // 81,920 B (5 layers bf16 W2^T)

  // setup: prep (zeroes deg) -> deg -> scan -> fill (all parallel kernels)
  k_prep<<<320, 256, 0, stream>>>(W1, W2, w1t, w2t, deg);
  k_deg<<<N_EDGES / 256, 256, 0, stream>>>(dstI, deg);
  k_scan<<<1, 1024, 0, stream>>>(deg, rowptr, cursor, batch, cntf, pooled);
  k_fill<<<N_EDGES / 256, 256, 0, stream>>>(srcI, dstI, cursor, src_sorted);

  for (int i = 0; i < N_LAYERS; i++) {
    k_mlp<<<(N_NODES + 63) / 64, 256, 0, stream>>>(x, hbuf, i == 0 ? 1 : 0, mlo, mhi,
                                                   w1t + (size_t)i * 8192, w2t + (size_t)i * 8192,
                                                   b1 + (size_t)i * 64, b2 + (size_t)i * 128);
    k_scatter<<<2 * NCHUNK, 256, 0, stream>>>(mlo, mhi, gbuf, rowptr, src_sorted, s1buf, s2buf);
    k_stats<<<N_NODES / STAT_CHUNK, 128, 0, stream>>>(gbuf, batch, s1buf, s2buf);
    if (i < N_LAYERS - 1) {
      k_apply<<<N_NODES * N_FEAT / 4 / 256, 256, 0, stream>>>(gbuf, hbuf, batch, s1buf, s2buf, cntf,
                                                              gnw + (size_t)i * 128, gnb + (size_t)i * 128,
                                                              gna + (size_t)i * 128, i > 0 ? 1 : 0);
    } else {
      k_apply_pool<<<N_NODES / 8, 256, 0, stream>>>(gbuf, hbuf, batch, s1buf, s2buf, cntf,
                                                    gnw + (size_t)i * 128, gnb + (size_t)i * 128,
                                                    gna + (size_t)i * 128, pooled);
    }
  }

  k_final<<<1, 256, 0, stream>>>(pooled, cntf, lw, lb, out);
}

// Round 11
// 330.430 us; speedup vs baseline: 1.0652x; 1.0652x over previous
//
#include <hip/hip_runtime.h>

#define N_NODES 20000
#define N_EDGES 320000
#define N_FEAT 128
#define MLP_HID 64
#define N_GRAPHS 16
#define N_LAYERS 5
#define EPS 1e-5f

typedef __attribute__((ext_vector_type(8))) short short8;   // 8 bf16 = 4 VGPRs (MFMA A/B frag)
typedef __attribute__((ext_vector_type(4))) float f32x4;    // MFMA C/D frag

__device__ inline float bf2f(unsigned short u) { return __uint_as_float(((unsigned)u) << 16); }
__device__ inline unsigned short f2bf(float f) {
  unsigned u = __float_as_uint(f);
  u += 0x7FFF + ((u >> 16) & 1);  // RNE
  return (unsigned short)(u >> 16);
}

// ---------------- weight prep: bf16 + transpose (once per call); also zeroes deg ----------------

__global__ __launch_bounds__(256) void k_prep(const float* __restrict__ W1, const float* __restrict__ W2,
                                              unsigned short* __restrict__ w1t, unsigned short* __restrict__ w2t,
                                              int* __restrict__ deg) {
  int idx = blockIdx.x * 256 + threadIdx.x;  // grid exact: 320*256 = 81920
  if (idx < N_NODES) deg[idx] = 0;
  if (idx < 40960) {
    int l = idx >> 13, rem = idx & 8191;
    int n = rem >> 7, k = rem & 127;
    w1t[idx] = f2bf(W1[l * 8192 + k * 64 + n]);
  } else {
    int j = idx - 40960;
    int l = j >> 13, rem = j & 8191;
    int n = rem >> 6, k = rem & 63;
    w2t[j] = f2bf(W2[l * 8192 + k * 128 + n]);
  }
}

// ---------------- CSR build ----------------

__global__ __launch_bounds__(256) void k_deg(const int* __restrict__ dst, int* __restrict__ deg) {
  int e = blockIdx.x * 256 + threadIdx.x;  // grid exact: 1250*256 = 320000
  atomicAdd(&deg[dst[e]], 1);
}

__global__ __launch_bounds__(1024) void k_scan(const int* __restrict__ deg, int* __restrict__ rowptr,
                                               int* __restrict__ cursor, const int* __restrict__ batch,
                                               float* __restrict__ cntf, float* __restrict__ pooled) {
  __shared__ int sdata[1024];
  __shared__ int spos[17];
  constexpr int CH = 20;  // 1024*20 = 20480 >= 20000
  int t = threadIdx.x;
  for (int i = t; i < N_GRAPHS * N_FEAT; i += 1024) pooled[i] = 0.0f;
  int base = t * CH;
  int loc[CH];
  int partial = 0;
#pragma unroll
  for (int i = 0; i < CH; i++) {
    int idx = base + i;
    int v = (idx < N_NODES) ? deg[idx] : 0;
    loc[i] = v;
    partial += v;
  }
  sdata[t] = partial;
  __syncthreads();
  for (int off = 1; off < 1024; off <<= 1) {
    int v = (t >= off) ? sdata[t - off] : 0;
    __syncthreads();
    sdata[t] += v;
    __syncthreads();
  }
  int run = sdata[t] - partial;  // exclusive prefix
#pragma unroll
  for (int i = 0; i < CH; i++) {
    int idx = base + i;
    if (idx < N_NODES) {
      rowptr[idx] = run;
      cursor[idx] = run;
      run += loc[i];
    }
  }
  if (t == 1023) rowptr[N_NODES] = sdata[1023];
  if (t < 17) {  // per-graph counts via binary search on sorted batch
    int lo = 0, hi = N_NODES;
    while (lo < hi) {
      int mid = (lo + hi) >> 1;
      if (batch[mid] < t) lo = mid + 1; else hi = mid;
    }
    spos[t] = lo;
  }
  __syncthreads();
  if (t < N_GRAPHS) cntf[t] = fmaxf((float)(spos[t + 1] - spos[t]), 1.0f);
}

__global__ __launch_bounds__(256) void k_fill(const int* __restrict__ src, const int* __restrict__ dst,
                                              int* __restrict__ cursor, unsigned short* __restrict__ src_sorted) {
  int e = blockIdx.x * 256 + threadIdx.x;  // grid exact
  int d = dst[e];
  int p = atomicAdd(&cursor[d], 1);
  src_sorted[p] = (unsigned short)src[e];  // N_NODES=20000 < 65536
}

// ---------------- per-node MLP via MFMA: m = relu(h@W1+b1)@W2+b2, m stored bf16 ----------------
// 64 nodes/block, 8 waves (512 thr): wave w -> row-group (w>>1)*16, nt-half (w&1).
// Same LDS as the 4-wave version; 2x waves/CU to hide staging + LDS latency.
// fp32in=1: hin is fp32 (layer 0 reads x); else bf16 (hbuf).

#define PADK 136  // 128+8 shorts: +16B row pad breaks LDS bank conflicts
#define PADH 72   // 64+8

__global__ __launch_bounds__(512) void k_mlp(const float* __restrict__ hinf,
                                             const unsigned short* __restrict__ hinb, int fp32in,
                                             unsigned short* __restrict__ mout,
                                             const unsigned short* __restrict__ w1t,
                                             const unsigned short* __restrict__ w2t,
                                             const float* __restrict__ b1, const float* __restrict__ b2) {
  __shared__ __align__(16) short hS[64 * PADK];   // h bf16; reused as m-out after phase 1
  __shared__ __align__(16) short w1S[64 * PADK];  // W1^T [n][k]
  __shared__ __align__(16) short hidS[64 * PADH]; // hidden [m][k]
  __shared__ __align__(16) short w2S[128 * PADH]; // W2^T [n][k]
  __shared__ float b1S[64];
  __shared__ float b2S[128];
  int t = threadIdx.x;
  int r0 = blockIdx.x * 64;  // grid 313: last block covers 32 valid rows
  if (fp32in) {  // stage h (fp32 global -> bf16 LDS)
#pragma unroll
    for (int i = 0; i < 4; i++) {
      int idx = t + i * 512;  // float4 id, 2048 total
      int row = idx >> 5, c4 = idx & 31;
      float4 v = (r0 + row < N_NODES) ? ((const float4*)hinf)[(size_t)(r0 + row) * 32 + c4]
                                      : make_float4(0.f, 0.f, 0.f, 0.f);
      ushort4 s;
      s.x = f2bf(v.x); s.y = f2bf(v.y); s.z = f2bf(v.z); s.w = f2bf(v.w);
      *(ushort4*)&hS[row * PADK + c4 * 4] = s;
    }
  } else {  // stage h (bf16 global -> bf16 LDS, pure copy)
#pragma unroll
    for (int i = 0; i < 2; i++) {
      int idx = t + i * 512;  // int4 id, 1024 total (64 rows x 16 chunks)
      int row = idx >> 4, c8 = idx & 15;
      int4 v = (r0 + row < N_NODES) ? ((const int4*)hinb)[(size_t)(r0 + row) * 16 + c8]
                                    : make_int4(0, 0, 0, 0);
      *(int4*)&hS[row * PADK + c8 * 8] = v;
    }
  }
  // stage W1t (64x128 shorts = 1024 16B chunks) and W2t (128x64)
#pragma unroll
  for (int i = 0; i < 2; i++) {
    int idx = t + i * 512;
    *(int4*)&w1S[(idx >> 4) * PADK + (idx & 15) * 8] = ((const int4*)w1t)[idx];
    *(int4*)&w2S[(idx >> 3) * PADH + (idx & 7) * 8] = ((const int4*)w2t)[idx];
  }
  if (t < 64) b1S[t] = b1[t];
  else if (t < 192) b2S[t - 64] = b2[t - 64];
  __syncthreads();

  int w = t >> 6, lane = t & 63, lm = lane & 15, quad = lane >> 4;
  int rowgrp = w >> 1, half = w & 1;
  int mrow = rowgrp * 16 + lm;          // A-operand row for this lane
  int orow = rowgrp * 16 + quad * 4;    // C/D base row for this lane

  // phase 1: hid[64][64] = relu(h @ W1 + b1); wave does nt = half*2 + {0,1}
  f32x4 zero = {0.f, 0.f, 0.f, 0.f};
  f32x4 acc[2] = {zero, zero};
#pragma unroll
  for (int k0 = 0; k0 < 128; k0 += 32) {
    short8 a = *(const short8*)&hS[mrow * PADK + k0 + quad * 8];
#pragma unroll
    for (int n2 = 0; n2 < 2; n2++) {
      int nt = half * 2 + n2;
      short8 b = *(const short8*)&w1S[(nt * 16 + lm) * PADK + k0 + quad * 8];
      acc[n2] = __builtin_amdgcn_mfma_f32_16x16x32_bf16(a, b, acc[n2], 0, 0, 0);
    }
  }
#pragma unroll
  for (int n2 = 0; n2 < 2; n2++) {
    int col = (half * 2 + n2) * 16 + lm;
    float bb = b1S[col];
#pragma unroll
    for (int r = 0; r < 4; r++)
      hidS[(orow + r) * PADH + col] = (short)f2bf(fmaxf(acc[n2][r] + bb, 0.0f));
  }
  __syncthreads();  // hidS ready; hS no longer read -> reusable as m-out

  // phase 2: m[64][128] = hid @ W2 + b2; wave does nt = half*4 + {0..3}
  f32x4 acc2[4] = {zero, zero, zero, zero};
#pragma unroll
  for (int k0 = 0; k0 < 64; k0 += 32) {
    short8 a = *(const short8*)&hidS[mrow * PADH + k0 + quad * 8];
#pragma unroll
    for (int n4 = 0; n4 < 4; n4++) {
      int nt = half * 4 + n4;
      short8 b = *(const short8*)&w2S[(nt * 16 + lm) * PADH + k0 + quad * 8];
      acc2[n4] = __builtin_amdgcn_mfma_f32_16x16x32_bf16(a, b, acc2[n4], 0, 0, 0);
    }
  }
#pragma unroll
  for (int n4 = 0; n4 < 4; n4++) {
    int col = (half * 4 + n4) * 16 + lm;
    float bb = b2S[col];
#pragma unroll
    for (int r = 0; r < 4; r++)
      hS[(orow + r) * PADK + col] = (short)f2bf(acc2[n4][r] + bb);
  }
  __syncthreads();
  // coalesced bf16 store of m
#pragma unroll
  for (int i = 0; i < 2; i++) {
    int idx = t + i * 512;
    int row = idx >> 4, cc = idx & 15;
    if (r0 + row < N_NODES)
      ((int4*)mout)[(size_t)(r0 + row) * 16 + cc] = *(const int4*)&hS[row * PADK + cc * 8];
  }
}

// ---------------- scatter-add: g[n] = m[n] + sum m[src[e]]; g stored bf16 ----------------

__global__ __launch_bounds__(256) void k_scatter(const unsigned short* __restrict__ mbf,
                                                 unsigned short* __restrict__ g,
                                                 const int* __restrict__ rowptr,
                                                 const unsigned short* __restrict__ srcs,
                                                 float* __restrict__ s1, float* __restrict__ s2) {
  if (blockIdx.x == 0) {  // zero stats accumulators (k_stats dispatches later)
    for (int i = threadIdx.x; i < N_GRAPHS * N_FEAT; i += 256) { s1[i] = 0.0f; s2[i] = 0.0f; }
  }
  int node = (blockIdx.x * 256 + threadIdx.x) >> 6;  // grid exact: 5000*4 waves
  int lane = threadIdx.x & 63;
  int quarter = lane >> 4;
  int q16 = lane & 15;
  const float4* m4 = (const float4*)mbf;
  float acc[8];
  union BU { float4 f; unsigned short u[8]; };
  if (quarter == 0) {  // self loop
    BU U; U.f = m4[(size_t)node * 16 + q16];
#pragma unroll
    for (int j = 0; j < 8; j++) acc[j] = bf2f(U.u[j]);
  } else {
#pragma unroll
    for (int j = 0; j < 8; j++) acc[j] = 0.0f;
  }
  int e = rowptr[node], e1 = rowptr[node + 1];
  for (; e + 16 <= e1; e += 16) {
    int i0 = srcs[e + quarter];
    int i1 = srcs[e + 4 + quarter];
    int i2 = srcs[e + 8 + quarter];
    int i3 = srcs[e + 12 + quarter];
    BU U0, U1, U2, U3;
    U0.f = m4[(size_t)i0 * 16 + q16];
    U1.f = m4[(size_t)i1 * 16 + q16];
    U2.f = m4[(size_t)i2 * 16 + q16];
    U3.f = m4[(size_t)i3 * 16 + q16];
#pragma unroll
    for (int j = 0; j < 8; j++)
      acc[j] += (bf2f(U0.u[j]) + bf2f(U1.u[j])) + (bf2f(U2.u[j]) + bf2f(U3.u[j]));
  }
  for (; e + 4 <= e1; e += 4) {
    BU U0; U0.f = m4[(size_t)srcs[e + quarter] * 16 + q16];
#pragma unroll
    for (int j = 0; j < 8; j++) acc[j] += bf2f(U0.u[j]);
  }
  if (e + quarter < e1) {
    BU U0; U0.f = m4[(size_t)srcs[e + quarter] * 16 + q16];
#pragma unroll
    for (int j = 0; j < 8; j++) acc[j] += bf2f(U0.u[j]);
  }
#pragma unroll
  for (int j = 0; j < 8; j++) {
    acc[j] += __shfl_xor(acc[j], 16);
    acc[j] += __shfl_xor(acc[j], 32);
  }
  if (quarter == 0) {
    union { int4 i4; unsigned short u[8]; } P;
#pragma unroll
    for (int j = 0; j < 8; j++) P.u[j] = f2bf(acc[j]);
    ((int4*)g)[(size_t)node * 16 + q16] = P.i4;  // 128 bf16 = 16 int4 per row
  }
}

// ---------------- one-pass segment stats over bf16 g: s1 = sum(g), s2 = sum(g^2) ----------------

#define STAT_CHUNK 8  // 2500 blocks * 8 = 20000 exact

__global__ __launch_bounds__(128) void k_stats(const unsigned short* __restrict__ in,
                                               const int* __restrict__ batch,
                                               float* __restrict__ s1, float* __restrict__ s2) {
  int n0 = blockIdx.x * STAT_CHUNK;
  int c = threadIdx.x;
  int curg = batch[n0];
  float a1 = 0.0f, a2 = 0.0f;
#pragma unroll
  for (int k = 0; k < STAT_CHUNK; k++) {
    int n = n0 + k;
    int gg = batch[n];
    if (gg != curg) {  // block-uniform branch (batch sorted)
      atomicAdd(&s1[curg * 128 + c], a1);
      atomicAdd(&s2[curg * 128 + c], a2);
      a1 = 0.0f; a2 = 0.0f;
      curg = gg;
    }
    float v = bf2f(in[(size_t)n * 128 + c]);
    a1 += v;
    a2 += v * v;
  }
  atomicAdd(&s1[curg * 128 + c], a1);
  atomicAdd(&s2[curg * 128 + c], a2);
}

// ---------------- normalize + affine + relu + residual; g,h bf16 ----------------
// var = E[(h - a*mean)^2] = E[h^2] - mean^2*(2a - a^2)

__global__ __launch_bounds__(256) void k_apply(const unsigned short* __restrict__ gin,
                                               unsigned short* __restrict__ h,
                                               const int* __restrict__ batch,
                                               const float* __restrict__ s1, const float* __restrict__ s2,
                                               const float* __restrict__ cntf,
                                               const float* __restrict__ w, const float* __restrict__ b,
                                               const float* __restrict__ a, int residual) {
  int idx = blockIdx.x * 256 + threadIdx.x;  // 4-channel index; grid exact: 2500*256 = 640,000
  int n = idx >> 5, c4 = idx & 31;
  int gg = batch[n];
  float invc = 1.0f / cntf[gg];
  float4 sm = ((const float4*)s1)[gg * 32 + c4];
  float4 se = ((const float4*)s2)[gg * 32 + c4];
  float4 av = ((const float4*)a)[c4];
  float4 wv = ((const float4*)w)[c4];
  float4 bv = ((const float4*)b)[c4];
  ushort4 gu = ((const ushort4*)gin)[idx];
  float4 gv = make_float4(bf2f(gu.x), bf2f(gu.y), bf2f(gu.z), bf2f(gu.w));
  float4 hv = make_float4(0.f, 0.f, 0.f, 0.f);
  if (residual) {
    ushort4 hu = ((const ushort4*)h)[idx];
    hv = make_float4(bf2f(hu.x), bf2f(hu.y), bf2f(hu.z), bf2f(hu.w));
  }
  float4 o;
#define APPLY1(X)                                                          \
  {                                                                        \
    float mean = sm.X * invc;                                              \
    float ex2 = se.X * invc;                                               \
    float ac = av.X;                                                       \
    float var = fmaxf(ex2 - mean * mean * (2.0f * ac - ac * ac), 0.0f);    \
    float d = gv.X - ac * mean;                                            \
    float y = wv.X * (d * rsqrtf(var + EPS)) + bv.X;                       \
    y = fmaxf(y, 0.0f);                                                    \
    o.X = residual ? (y + hv.X) : y;                                       \
  }
  APPLY1(x) APPLY1(y) APPLY1(z) APPLY1(w)
#undef APPLY1
  ushort4 ou;
  ou.x = f2bf(o.x); ou.y = f2bf(o.y); ou.z = f2bf(o.z); ou.w = f2bf(o.w);
  ((ushort4*)h)[idx] = ou;
}

// ---------------- last layer: apply + pooled segment-sum (h never materialized) ----------------

__global__ __launch_bounds__(256) void k_apply_pool(const unsigned short* __restrict__ gin,
                                                    const unsigned short* __restrict__ h,
                                                    const int* __restrict__ batch,
                                                    const float* __restrict__ s1, const float* __restrict__ s2,
                                                    const float* __restrict__ cntf,
                                                    const float* __restrict__ gw, const float* __restrict__ gb,
                                                    const float* __restrict__ ga,
                                                    float* __restrict__ pooled) {
  __shared__ float pS[8][128];
  int t = threadIdx.x;
  int idx = blockIdx.x * 256 + t;  // 4-channel index; grid exact: 2500*256
  int n = idx >> 5, c4 = idx & 31;
  int gg = batch[n];
  float invc = 1.0f / cntf[gg];
  float4 sm = ((const float4*)s1)[gg * 32 + c4];
  float4 se = ((const float4*)s2)[gg * 32 + c4];
  float4 av = ((const float4*)ga)[c4];
  float4 wv = ((const float4*)gw)[c4];
  float4 bv = ((const float4*)gb)[c4];
  ushort4 gu = ((const ushort4*)gin)[idx];
  float4 gv = make_float4(bf2f(gu.x), bf2f(gu.y), bf2f(gu.z), bf2f(gu.w));
  ushort4 hu = ((const ushort4*)h)[idx];  // residual (layer 5 always has it)
  float4 hv = make_float4(bf2f(hu.x), bf2f(hu.y), bf2f(hu.z), bf2f(hu.w));
  float4 o;
#define APPLY1(X)                                                          \
  {                                                                        \
    float mean = sm.X * invc;                                              \
    float ex2 = se.X * invc;                                               \
    float ac = av.X;                                                       \
    float var = fmaxf(ex2 - mean * mean * (2.0f * ac - ac * ac), 0.0f);    \
    float d = gv.X - ac * mean;                                            \
    float y = wv.X * (d * rsqrtf(var + EPS)) + bv.X;                       \
    y = fmaxf(y, 0.0f);                                                    \
    o.X = y + hv.X;                                                        \
  }
  APPLY1(x) APPLY1(y) APPLY1(z) APPLY1(w)
#undef APPLY1
  *(float4*)&pS[t >> 5][c4 * 4] = o;
  __syncthreads();
  int n0 = blockIdx.x * 8;
  int gA = batch[n0], gB = batch[n0 + 7];
  if (t < 128) {
    if (gA == gB) {
      float s = 0.f;
#pragma unroll
      for (int ww = 0; ww < 8; ww++) s += pS[ww][t];
      atomicAdd(&pooled[gA * 128 + t], s);
    } else {
#pragma unroll
      for (int ww = 0; ww < 8; ww++) atomicAdd(&pooled[batch[n0 + ww] * 128 + t], pS[ww][t]);
    }
  }
}

// ---------------- final pooled @ lin_w + lin_b ----------------

__global__ __launch_bounds__(256) void k_final(const float* __restrict__ pooled, const float* __restrict__ cntf,
                                               const float* __restrict__ lw, const float* __restrict__ lb,
                                               float* __restrict__ out) {
  int lane = threadIdx.x & 63, wave = threadIdx.x >> 6;
  for (int gi = 0; gi < 4; gi++) {
    int gidx = wave * 4 + gi;
    float s = pooled[gidx * 128 + lane] * lw[lane] + pooled[gidx * 128 + 64 + lane] * lw[64 + lane];
    for (int o = 32; o >= 1; o >>= 1) s += __shfl_down(s, o);
    if (lane == 0) out[gidx] = s / cntf[gidx] + lb[0];
  }
}

// ---------------- host ----------------

extern "C" void kernel_launch(void* const* d_in, const int* in_sizes, int n_in,
                              void* d_out, int out_size, void* d_ws, size_t ws_size,
                              hipStream_t stream) {
  const float* x = (const float*)d_in[0];
  const int* ei = (const int*)d_in[1];
  const int* batch = (const int*)d_in[2];
  const float* W1 = (const float*)d_in[3];
  const float* b1 = (const float*)d_in[4];
  const float* W2 = (const float*)d_in[5];
  const float* b2 = (const float*)d_in[6];
  const float* gnw = (const float*)d_in[7];
  const float* gnb = (const float*)d_in[8];
  const float* gna = (const float*)d_in[9];
  const float* lw = (const float*)d_in[10];
  const float* lb = (const float*)d_in[11];
  float* out = (float*)d_out;

  const int* srcI = ei;
  const int* dstI = ei + N_EDGES;

  char* p = (char*)d_ws;
  unsigned short* hbuf = (unsigned short*)(p + 0);         // 5,120,000 B (bf16)
  unsigned short* mbuf = (unsigned short*)(p + 10240000);  // 5,120,000 B (bf16)
  unsigned short* gbuf = (unsigned short*)(p + 20480000);  // 5,120,000 B (bf16)
  unsigned short* src_sorted = (unsigned short*)(p + 30720000);  // 640,000 B (u16 node ids)
  int* rowptr = (int*)(p + 32000000);
  int* cursor = (int*)(p + 32080128);
  int* deg = (int*)(p + 32160256);
  float* cntf = (float*)(p + 32240512);
  float* s1buf = (float*)(p + 32240640);                   // 8192 B
  float* s2buf = (float*)(p + 32248832);                   // 8192 B
  float* pooled = (float*)(p + 32257024);                  // 8192 B
  unsigned short* w1t = (unsigned short*)(p + 32265216);   // 81,920 B (5 layers bf16 W1^T)
  unsigned short* w2t = (unsigned short*)(p + 32347136);   // 81,920 B (5 layers bf16 W2^T)

  // setup: prep (zeroes deg) -> deg -> scan -> fill (all parallel kernels)
  k_prep<<<320, 256, 0, stream>>>(W1, W2, w1t, w2t, deg);
  k_deg<<<N_EDGES / 256, 256, 0, stream>>>(dstI, deg);
  k_scan<<<1, 1024, 0, stream>>>(deg, rowptr, cursor, batch, cntf, pooled);
  k_fill<<<N_EDGES / 256, 256, 0, stream>>>(srcI, dstI, cursor, src_sorted);

  for (int i = 0; i < N_LAYERS; i++) {
    k_mlp<<<(N_NODES + 63) / 64, 512, 0, stream>>>(x, hbuf, i == 0 ? 1 : 0, mbuf,
                                                   w1t + (size_t)i * 8192, w2t + (size_t)i * 8192,
                                                   b1 + (size_t)i * 64, b2 + (size_t)i * 128);
    k_scatter<<<N_NODES / 4, 256, 0, stream>>>(mbuf, gbuf, rowptr, src_sorted, s1buf, s2buf);
    k_stats<<<N_NODES / STAT_CHUNK, 128, 0, stream>>>(gbuf, batch, s1buf, s2buf);
    if (i < N_LAYERS - 1) {
      k_apply<<<N_NODES * N_FEAT / 4 / 256, 256, 0, stream>>>(gbuf, hbuf, batch, s1buf, s2buf, cntf,
                                                              gnw + (size_t)i * 128, gnb + (size_t)i * 128,
                                                              gna + (size_t)i * 128, i > 0 ? 1 : 0);
    } else {
      k_apply_pool<<<N_NODES / 8, 256, 0, stream>>>(gbuf, hbuf, batch, s1buf, s2buf, cntf,
                                                    gnw + (size_t)i * 128, gnb + (size_t)i * 128,
                                                    gna + (size_t)i * 128, pooled);
    }
  }

  k_final<<<1, 256, 0, stream>>>(pooled, cntf, lw, lb, out);
}